// Round 4
// baseline (2368.766 us; speedup 1.0000x reference)
//
#include <hip/hip_runtime.h>
#include <math.h>

namespace {
constexpr int kS = 2048;
constexpr int kD = 64;
constexpr int kBH = 32;              // B*H = 2*16
constexpr int kTopK = 32;
constexpr int kBins = 4096;          // 12-bit radix on sortable float bits
constexpr int kMaxCand = 512;
constexpr size_t kCtxElems  = (size_t)kBH * kS * kD;   // 4,194,304
constexpr size_t kAttnElems = (size_t)kBH * kS * kS;   // 134,217,728
}

__device__ __forceinline__ unsigned sortable_bits(float x) {
  unsigned u = __float_as_uint(x);
  return u ^ ((u & 0x80000000u) ? 0xFFFFFFFFu : 0x80000000u);
}

// ---------------------------------------------------------------------------
// Kernel 1: scores = Q K^T / 8, fp32, SEQUENTIAL-k FMA accumulation
// (k ascending, single accumulator chain -> v_fmac_f32; this is the bit
// pattern of a BLAS sgemm microkernel / FMA-contracted C loop). Written into
// the attn region of d_out. Selection in kernel 2 uses these exact bits.
// ---------------------------------------------------------------------------
__global__ __launch_bounds__(256) void qk_scores(const float* __restrict__ q,
                                                 const float* __restrict__ k,
                                                 float* __restrict__ scores) {
  __shared__ float Qs[64][68];   // [row][kk]
  __shared__ float KsT[64][68];  // [kk][col]
  const int bh  = blockIdx.z;
  const int q0  = blockIdx.y * 64;
  const int k0  = blockIdx.x * 64;
  const int tid = threadIdx.x;
  const float* qg = q + ((size_t)bh * kS + q0) * kD;
  const float* kg = k + ((size_t)bh * kS + k0) * kD;

#pragma unroll
  for (int rnd = 0; rnd < 4; ++rnd) {
    int flat = rnd * 1024 + tid * 4;
    int r = flat >> 6;       // tile row (q-row / k-row)
    int c = flat & 63;       // kk
    float4 qv = *(const float4*)(qg + r * kD + c);
    *(float4*)(&Qs[r][c]) = qv;
    float4 kv = *(const float4*)(kg + r * kD + c);
    KsT[c + 0][r] = kv.x;
    KsT[c + 1][r] = kv.y;
    KsT[c + 2][r] = kv.z;
    KsT[c + 3][r] = kv.w;
  }
  __syncthreads();

  const int ty = tid >> 4;   // 0..15 -> q rows ty*4..ty*4+3
  const int tx = tid & 15;   // 0..15 -> k cols tx*4..tx*4+3
  float acc[4][4] = {};
#pragma unroll
  for (int kk = 0; kk < 64; kk += 4) {
    float4 a[4], b[4];
#pragma unroll
    for (int i = 0; i < 4; ++i) a[i] = *(const float4*)(&Qs[ty * 4 + i][kk]);
#pragma unroll
    for (int u = 0; u < 4; ++u) b[u] = *(const float4*)(&KsT[kk + u][tx * 4]);
    const float* Af = (const float*)a;  // Af[i*4+u]
    const float* Bf = (const float*)b;  // Bf[u*4+j]
    // k strictly ascending for each (i,j): kk outer, u inner ascending.
#pragma unroll
    for (int i = 0; i < 4; ++i)
#pragma unroll
      for (int u = 0; u < 4; ++u)
#pragma unroll
        for (int j = 0; j < 4; ++j)
          acc[i][j] += Af[i * 4 + u] * Bf[u * 4 + j];
  }

#pragma unroll
  for (int i = 0; i < 4; ++i) {
    float4 o = make_float4(acc[i][0] * 0.125f, acc[i][1] * 0.125f,
                           acc[i][2] * 0.125f, acc[i][3] * 0.125f);
    *(float4*)(scores + ((size_t)bh * kS + q0 + ty * 4 + i) * kS + k0 + tx * 4) = o;
  }
}

// ---------------------------------------------------------------------------
// Kernel 2: per query row — selection done ENTIRELY on kernel-1's fp32 score
// bits, with exact reference semantics: t = 32nd-largest fp32 VALUE
// (duplicates counted), keep = score >= t (fp32 ties kept). Softmax/ctx in
// fp64 (values, not selection — diffs ~1e-7 vs 2% thresholds).
// ---------------------------------------------------------------------------
__global__ __launch_bounds__(256) void topk_softmax(const float* __restrict__ v,
                                                    float* __restrict__ ctx,
                                                    float* __restrict__ attn,
                                                    float* __restrict__ mask) {
  const int row = blockIdx.x;      // bh*2048 + qi
  const int bh  = row >> 11;
  const int tid = threadIdx.x;

  __shared__ float    s_val[kS];        // scores, later attn values
  __shared__ float    s_msk[kS];        // mask values (1.0 = masked)
  __shared__ unsigned s_hist[kBins];
  __shared__ unsigned s_scan[256];
  __shared__ int      s_cidx[kMaxCand];
  __shared__ float    s_cval[kMaxCand];
  __shared__ double   s_w[kMaxCand];
  __shared__ unsigned s_nc;
  __shared__ int      s_bstar;
  __shared__ float    s_t32, s_mx;
  __shared__ double   s_Z;

#pragma unroll
  for (int i = 0; i < kBins / 256; ++i) s_hist[tid + i * 256] = 0u;
  if (tid == 0) s_nc = 0u;

  const float* srow = attn + (size_t)row * kS;   // scores written by kernel 1
  float4 l0 = *(const float4*)(srow + tid * 4);
  float4 l1 = *(const float4*)(srow + 1024 + tid * 4);
  *(float4*)(&s_val[tid * 4])        = l0;
  *(float4*)(&s_val[1024 + tid * 4]) = l1;
  __syncthreads();  // hist zeroed before atomics

  float locv[8] = {l0.x, l0.y, l0.z, l0.w, l1.x, l1.y, l1.z, l1.w};
  int   loce[8];
#pragma unroll
  for (int j = 0; j < 8; ++j) {
    loce[j] = (j < 4) ? (tid * 4 + j) : (1024 + tid * 4 + (j - 4));
    atomicAdd(&s_hist[sortable_bits(locv[j]) >> 20], 1u);
  }
  __syncthreads();

  // Suffix (descending-value cumulative) counts over 256 chunks of 16 bins.
  unsigned lsum = 0;
#pragma unroll
  for (int j = 0; j < kBins / 256; ++j) lsum += s_hist[tid * (kBins / 256) + j];
  s_scan[tid] = lsum;
  __syncthreads();
  unsigned sfx = lsum;
  for (int off = 1; off < 256; off <<= 1) {
    unsigned nb = (tid + off < 256) ? s_scan[tid + off] : 0u;
    __syncthreads();
    sfx += nb;
    s_scan[tid] = sfx;
    __syncthreads();
  }
  unsigned above_chunk = (tid < 255) ? s_scan[tid + 1] : 0u;
  if (sfx >= (unsigned)kTopK && above_chunk < (unsigned)kTopK) {
    unsigned run = above_chunk;            // count strictly above current bin
    for (int j = kBins / 256 - 1; j >= 0; --j) {
      unsigned h = s_hist[tid * (kBins / 256) + j];
      if (run < (unsigned)kTopK && run + h >= (unsigned)kTopK)
        s_bstar = tid * (kBins / 256) + j;
      run += h;
    }
  }
  __syncthreads();
  const int bstar = s_bstar;

  // Candidates: all elements in bins >= bstar. The fp32 top-32 (by value,
  // duplicates counted) is provably contained here: histogram and ranking
  // use the SAME fp32 bits.
#pragma unroll
  for (int j = 0; j < 8; ++j) {
    if ((int)(sortable_bits(locv[j]) >> 20) >= bstar) {
      unsigned pos = atomicAdd(&s_nc, 1u);
      if (pos < (unsigned)kMaxCand) { s_cidx[pos] = loce[j]; s_cval[pos] = locv[j]; }
    }
  }
  __syncthreads();
  const int m = (int)min(s_nc, (unsigned)kMaxCand);

  // 32nd-largest fp32 VALUE t: g = #strictly-greater, e = #equal;
  // the value with g < 32 <= g+e is t (all holders write identical bits).
  for (int c = tid; c < m; c += 256) {
    float x = s_cval[c];
    int g = 0, e = 0;
    for (int j2 = 0; j2 < m; ++j2) {
      float y = s_cval[j2];
      g += (y > x);
      e += (y == x);
    }
    if (g == 0) s_mx = x;                        // max (dup-safe: same bits)
    if (g < kTopK && g + e >= kTopK) s_t32 = x;  // threshold value
  }
  __syncthreads();
  const float t32 = s_t32;
  const double mx = (double)s_mx;
  for (int c = tid; c < m; c += 256)
    s_w[c] = (s_cval[c] >= t32) ? exp((double)s_cval[c] - mx) : 0.0;
  __syncthreads();
  if (tid == 0) {
    double z = 0.0;
    for (int c2 = 0; c2 < m; ++c2) z += s_w[c2];
    s_Z = z;
  }
  // Default fill while tid 0 sums Z.
#pragma unroll
  for (int j = 0; j < 8; ++j) { s_val[loce[j]] = 0.0f; s_msk[loce[j]] = 1.0f; }
  __syncthreads();
  const double invZ = 1.0 / s_Z;
  for (int c = tid; c < m; c += 256) {
    if (s_w[c] > 0.0) {
      int e2 = s_cidx[c];
      s_val[e2] = (float)(s_w[c] * invZ);
      s_msk[e2] = 0.0f;
    }
  }
  __syncthreads();

  float* arow = attn + (size_t)row * kS;
  float* mrow = mask + (size_t)row * kS;
  *(float4*)(arow + tid * 4)        = *(const float4*)(&s_val[tid * 4]);
  *(float4*)(arow + 1024 + tid * 4) = *(const float4*)(&s_val[1024 + tid * 4]);
  *(float4*)(mrow + tid * 4)        = *(const float4*)(&s_msk[tid * 4]);
  *(float4*)(mrow + 1024 + tid * 4) = *(const float4*)(&s_msk[1024 + tid * 4]);

  // context[d] = sum over kept candidates of attn * v[k][d]; one wave, lane=d.
  if (tid < kD) {
    double acc = 0.0;
    for (int c = 0; c < m; ++c) {
      if (s_w[c] > 0.0) {
        double a = s_w[c] * invZ;
        acc += a * (double)v[((size_t)bh * kS + s_cidx[c]) * kD + tid];
      }
    }
    ctx[(size_t)row * kD + tid] = (float)acc;
  }
}

extern "C" void kernel_launch(void* const* d_in, const int* in_sizes, int n_in,
                              void* d_out, int out_size, void* d_ws, size_t ws_size,
                              hipStream_t stream) {
  const float* q = (const float*)d_in[0];
  const float* k = (const float*)d_in[1];
  const float* v = (const float*)d_in[2];
  float* out  = (float*)d_out;
  float* ctx  = out;
  float* attn = out + kCtxElems;
  float* mask = attn + kAttnElems;

  dim3 g1(kS / 64, kS / 64, kBH);
  qk_scores<<<g1, 256, 0, stream>>>(q, k, attn);
  topk_softmax<<<dim3(kBH * kS), 256, 0, stream>>>(v, ctx, attn, mask);
}

// Round 5
// 1442.551 us; speedup vs baseline: 1.6421x; 1.6421x over previous
//
#include <hip/hip_runtime.h>
#include <math.h>

namespace {
constexpr int kS = 2048;
constexpr int kD = 64;
constexpr int kBH = 32;              // B*H = 2*16
constexpr int kTopK = 32;
constexpr int kBins = 4096;          // 12-bit radix on sortable float bits
constexpr int kMaxCand = 256;        // cap for values sharing the pivot bin
constexpr int kKeepCap = 64;         // cap for kept (idx, weight) list
constexpr size_t kCtxElems  = (size_t)kBH * kS * kD;   // 4,194,304
constexpr size_t kAttnElems = (size_t)kBH * kS * kS;   // 134,217,728
}

__device__ __forceinline__ unsigned sortable_bits(float x) {
  unsigned u = __float_as_uint(x);
  return u ^ ((u & 0x80000000u) ? 0xFFFFFFFFu : 0x80000000u);
}

// ---------------------------------------------------------------------------
// Kernel 1: scores = Q K^T / 8, fp32, SEQUENTIAL-k FMA accumulation.
// FROZEN — these exact bits feed the fp32 top-k selection that matches the
// numpy reference (round 4 pass). Do not alter accumulation order/tiling.
// ---------------------------------------------------------------------------
__global__ __launch_bounds__(256) void qk_scores(const float* __restrict__ q,
                                                 const float* __restrict__ k,
                                                 float* __restrict__ scores) {
  __shared__ float Qs[64][68];   // [row][kk]
  __shared__ float KsT[64][68];  // [kk][col]
  const int bh  = blockIdx.z;
  const int q0  = blockIdx.y * 64;
  const int k0  = blockIdx.x * 64;
  const int tid = threadIdx.x;
  const float* qg = q + ((size_t)bh * kS + q0) * kD;
  const float* kg = k + ((size_t)bh * kS + k0) * kD;

#pragma unroll
  for (int rnd = 0; rnd < 4; ++rnd) {
    int flat = rnd * 1024 + tid * 4;
    int r = flat >> 6;       // tile row (q-row / k-row)
    int c = flat & 63;       // kk
    float4 qv = *(const float4*)(qg + r * kD + c);
    *(float4*)(&Qs[r][c]) = qv;
    float4 kv = *(const float4*)(kg + r * kD + c);
    KsT[c + 0][r] = kv.x;
    KsT[c + 1][r] = kv.y;
    KsT[c + 2][r] = kv.z;
    KsT[c + 3][r] = kv.w;
  }
  __syncthreads();

  const int ty = tid >> 4;   // 0..15 -> q rows ty*4..ty*4+3
  const int tx = tid & 15;   // 0..15 -> k cols tx*4..tx*4+3
  float acc[4][4] = {};
#pragma unroll
  for (int kk = 0; kk < 64; kk += 4) {
    float4 a[4], b[4];
#pragma unroll
    for (int i = 0; i < 4; ++i) a[i] = *(const float4*)(&Qs[ty * 4 + i][kk]);
#pragma unroll
    for (int u = 0; u < 4; ++u) b[u] = *(const float4*)(&KsT[kk + u][tx * 4]);
    const float* Af = (const float*)a;  // Af[i*4+u]
    const float* Bf = (const float*)b;  // Bf[u*4+j]
    // k strictly ascending for each (i,j): kk outer, u inner ascending.
#pragma unroll
    for (int i = 0; i < 4; ++i)
#pragma unroll
      for (int u = 0; u < 4; ++u)
#pragma unroll
        for (int j = 0; j < 4; ++j)
          acc[i][j] += Af[i * 4 + u] * Bf[u * 4 + j];
  }

#pragma unroll
  for (int i = 0; i < 4; ++i) {
    float4 o = make_float4(acc[i][0] * 0.125f, acc[i][1] * 0.125f,
                           acc[i][2] * 0.125f, acc[i][3] * 0.125f);
    *(float4*)(scores + ((size_t)bh * kS + q0 + ty * 4 + i) * kS + k0 + tx * 4) = o;
  }
}

// ---------------------------------------------------------------------------
// Kernel 2 (rewritten): one 256-thread block per query row. Scores live in
// registers; selection semantics identical to the round-4 pass:
//   t32 = 32nd-largest fp32 VALUE (duplicates counted), keep = score >= t32.
// Equal fp32 values share a radix bin, so ranking only the pivot-bin members
// with g_above carried from the scan reproduces the full (g, e) ranking.
// Slimmed LDS (~17.8 KB), 7 barriers, fp32 softmax, coalesced ctx.
// ---------------------------------------------------------------------------
__global__ __launch_bounds__(256) void topk_softmax(const float* __restrict__ v,
                                                    float* __restrict__ ctx,
                                                    float* __restrict__ attn,
                                                    float* __restrict__ mask) {
  const int row  = blockIdx.x;     // bh*2048 + qi
  const int bh   = row >> 11;
  const int tid  = threadIdx.x;
  const int lane = tid & 63;
  const int wid  = tid >> 6;

  __shared__ unsigned s_hist[kBins];       // 16 KB
  __shared__ float    s_cand[kMaxCand];    // 1 KB
  __shared__ int      s_kidx[kKeepCap];
  __shared__ float    s_kw[kKeepCap];
  __shared__ float    s_wmax[4], s_wsum[4];
  __shared__ unsigned s_T[4];
  __shared__ unsigned s_nc, s_nk;
  __shared__ int      s_bstar, s_gabove;
  __shared__ float    s_t32;

  // P0: load scores (registers) + zero hist.
  const float* srow = attn + (size_t)row * kS;   // scores from kernel 1
  float4 l0 = *(const float4*)(srow + tid * 4);
  float4 l1 = *(const float4*)(srow + 1024 + tid * 4);
  float locv[8] = {l0.x, l0.y, l0.z, l0.w, l1.x, l1.y, l1.z, l1.w};
  int   loce[8];
#pragma unroll
  for (int j = 0; j < 8; ++j)
    loce[j] = (j < 4) ? (tid * 4 + j) : (1024 + tid * 4 + (j - 4));
#pragma unroll
  for (int i = 0; i < 4; ++i)
    *(uint4*)(&s_hist[tid * 16 + i * 4]) = make_uint4(0u, 0u, 0u, 0u);
  if (tid == 0) { s_nc = 0u; s_nk = 0u; }
  __syncthreads();

  // P1: histogram + per-wave max.
  unsigned bins[8];
  float pmax = locv[0];
#pragma unroll
  for (int j = 0; j < 8; ++j) {
    bins[j] = sortable_bits(locv[j]) >> 20;
    atomicAdd(&s_hist[bins[j]], 1u);
    pmax = fmaxf(pmax, locv[j]);
  }
#pragma unroll
  for (int off = 32; off >= 1; off >>= 1)
    pmax = fmaxf(pmax, __shfl_xor(pmax, off));
  if (lane == 0) s_wmax[wid] = pmax;
  __syncthreads();

  // P2: chunk sums (16 bins/thread) + in-wave suffix scan via shfl.
  unsigned lsum = 0;
#pragma unroll
  for (int j = 0; j < 16; ++j) lsum += s_hist[tid * 16 + j];
  unsigned sfx = lsum;
#pragma unroll
  for (int off = 1; off < 64; off <<= 1) {
    unsigned z = __shfl_down(sfx, off);
    if (lane + off < 64) sfx += z;
  }
  if (lane == 0) s_T[wid] = sfx;   // this wave's 64-chunk total
  __syncthreads();

  // P3: global suffix, locate pivot bin bstar and g_above.
  unsigned hi = 0;
#pragma unroll
  for (int w = 0; w < 4; ++w)
    if (w > wid) hi += s_T[w];
  unsigned gsfx  = sfx + hi;        // inclusive suffix (chunks >= mine)
  unsigned above = gsfx - lsum;     // exclusive
  if (gsfx >= (unsigned)kTopK && above < (unsigned)kTopK) {
    unsigned run = above;
    for (int j = 15; j >= 0; --j) {
      unsigned h = s_hist[tid * 16 + j];
      if (run < (unsigned)kTopK && run + h >= (unsigned)kTopK) {
        s_bstar  = tid * 16 + j;
        s_gabove = (int)run;        // elements in bins strictly above pivot
      }
      run += h;
    }
  }
  __syncthreads();
  const int   bstar  = s_bstar;
  const int   gabove = s_gabove;
  const float mx = fmaxf(fmaxf(s_wmax[0], s_wmax[1]),
                         fmaxf(s_wmax[2], s_wmax[3]));

  // P4: collect pivot-bin values.
#pragma unroll
  for (int j = 0; j < 8; ++j) {
    if ((int)bins[j] == bstar) {
      unsigned pos = atomicAdd(&s_nc, 1u);
      if (pos < (unsigned)kMaxCand) s_cand[pos] = locv[j];
    }
  }
  __syncthreads();
  const int m2 = (int)min(s_nc, (unsigned)kMaxCand);

  // P5: t32 = value with gabove+g < 32 <= gabove+g+e (equal values all share
  // the pivot bin, so e counted here is complete).
  for (int c = tid; c < m2; c += 256) {
    float x = s_cand[c];
    int g = 0, e = 0;
    for (int j2 = 0; j2 < m2; ++j2) {
      float y = s_cand[j2];
      g += (y > x);
      e += (y == x);
    }
    int G = gabove + g;
    if (G < kTopK && G + e >= kTopK) s_t32 = x;
  }
  __syncthreads();
  const float t32 = s_t32;

  // P6: weights, partial Z, kept-list for ctx.
  float w8[8];
  float psum = 0.0f;
#pragma unroll
  for (int j = 0; j < 8; ++j) {
    bool keep = (locv[j] >= t32);
    float wv = keep ? __expf(locv[j] - mx) : 0.0f;
    w8[j] = wv;
    psum += wv;
    if (keep) {
      unsigned p = atomicAdd(&s_nk, 1u);
      if (p < (unsigned)kKeepCap) { s_kidx[p] = loce[j]; s_kw[p] = wv; }
    }
  }
#pragma unroll
  for (int off = 32; off >= 1; off >>= 1)
    psum += __shfl_xor(psum, off);
  if (lane == 0) s_wsum[wid] = psum;
  __syncthreads();

  const float Z = s_wsum[0] + s_wsum[1] + s_wsum[2] + s_wsum[3];
  const float invZ = 1.0f / Z;

  // P7: write attn + mask straight from registers (coalesced float4).
  float* arow = attn + (size_t)row * kS;
  float* mrow = mask + (size_t)row * kS;
  float4 a0 = make_float4(w8[0] * invZ, w8[1] * invZ, w8[2] * invZ, w8[3] * invZ);
  float4 a1 = make_float4(w8[4] * invZ, w8[5] * invZ, w8[6] * invZ, w8[7] * invZ);
  float4 m0 = make_float4(locv[0] >= t32 ? 0.f : 1.f, locv[1] >= t32 ? 0.f : 1.f,
                          locv[2] >= t32 ? 0.f : 1.f, locv[3] >= t32 ? 0.f : 1.f);
  float4 m1 = make_float4(locv[4] >= t32 ? 0.f : 1.f, locv[5] >= t32 ? 0.f : 1.f,
                          locv[6] >= t32 ? 0.f : 1.f, locv[7] >= t32 ? 0.f : 1.f);
  *(float4*)(arow + tid * 4)        = a0;
  *(float4*)(arow + 1024 + tid * 4) = a1;
  *(float4*)(mrow + tid * 4)        = m0;
  *(float4*)(mrow + 1024 + tid * 4) = m1;

  // P8: context via wave 0 (lane = d), coalesced v reads, ~32 kept rows.
  if (tid < kD) {
    const int nk = (int)min(s_nk, (unsigned)kKeepCap);
    float acc = 0.0f;
    for (int c = 0; c < nk; ++c)
      acc += s_kw[c] * v[((size_t)bh * kS + s_kidx[c]) * kD + tid];
    ctx[(size_t)row * kD + tid] = acc * invZ;
  }
}

extern "C" void kernel_launch(void* const* d_in, const int* in_sizes, int n_in,
                              void* d_out, int out_size, void* d_ws, size_t ws_size,
                              hipStream_t stream) {
  const float* q = (const float*)d_in[0];
  const float* k = (const float*)d_in[1];
  const float* v = (const float*)d_in[2];
  float* out  = (float*)d_out;
  float* ctx  = out;
  float* attn = out + kCtxElems;
  float* mask = attn + kAttnElems;

  dim3 g1(kS / 64, kS / 64, kBH);
  qk_scores<<<g1, 256, 0, stream>>>(q, k, attn);
  topk_softmax<<<dim3(kBH * kS), 256, 0, stream>>>(v, ctx, attn, mask);
}

// Round 6
// 1437.669 us; speedup vs baseline: 1.6476x; 1.0034x over previous
//
#include <hip/hip_runtime.h>
#include <math.h>

namespace {
constexpr int kS = 2048;
constexpr int kD = 64;
constexpr int kBH = 32;              // B*H = 2*16
constexpr int kTopK = 32;
constexpr int kBins = 4096;          // 12-bit radix on sortable float bits
constexpr int kMaxCand = 256;        // cap for values sharing the pivot bin
constexpr int kKeepCap = 64;         // cap for kept (idx, weight) list
constexpr size_t kCtxElems  = (size_t)kBH * kS * kD;   // 4,194,304
constexpr size_t kAttnElems = (size_t)kBH * kS * kS;   // 134,217,728
}

__device__ __forceinline__ unsigned sortable_bits(float x) {
  unsigned u = __float_as_uint(x);
  return u ^ ((u & 0x80000000u) ? 0xFFFFFFFFu : 0x80000000u);
}

// ---------------------------------------------------------------------------
// Kernel 1: scores = Q K^T / 8, fp32.
// BIT-EXACTNESS INVARIANT (round-4 pass): every score element is a single
// fp32 accumulator chain `acc += a*b` with k STRICTLY ASCENDING, scaled by
// 0.125f at the end. Tile/microtile shape is free; the per-element chain is
// frozen. This round: 128x128 tile, 8x8 microtile (LDS bytes/FLOP 2 -> 0.5),
// both tiles stored transposed [kk][row] (pad 132: 16B-aligned rows, wave's
// row-groups land on distinct banks).
// ---------------------------------------------------------------------------
__global__ __launch_bounds__(256) void qk_scores(const float* __restrict__ q,
                                                 const float* __restrict__ k,
                                                 float* __restrict__ scores) {
  __shared__ float QsT[64][132];  // [kk][q-row]  33.8 KB
  __shared__ float KsT[64][132];  // [kk][k-row]  33.8 KB
  const int bh  = blockIdx.z;
  const int q0  = blockIdx.y * 128;
  const int k0  = blockIdx.x * 128;
  const int tid = threadIdx.x;
  const float* qg = q + ((size_t)bh * kS + q0) * kD;   // 128 rows x 64
  const float* kg = k + ((size_t)bh * kS + k0) * kD;

#pragma unroll
  for (int rnd = 0; rnd < 8; ++rnd) {
    int flat = rnd * 1024 + tid * 4;   // 128*64 = 8192 floats per tile
    int r = flat >> 6;                 // tile row
    int c = flat & 63;                 // kk
    float4 qv = *(const float4*)(qg + flat);
    QsT[c + 0][r] = qv.x;
    QsT[c + 1][r] = qv.y;
    QsT[c + 2][r] = qv.z;
    QsT[c + 3][r] = qv.w;
    float4 kv = *(const float4*)(kg + flat);
    KsT[c + 0][r] = kv.x;
    KsT[c + 1][r] = kv.y;
    KsT[c + 2][r] = kv.z;
    KsT[c + 3][r] = kv.w;
  }
  __syncthreads();

  const int ty8 = (tid >> 4) * 8;   // q rows ty8..ty8+7
  const int tx8 = (tid & 15) * 8;   // k cols tx8..tx8+7
  float acc[8][8] = {};
#pragma unroll
  for (int kk = 0; kk < 64; kk += 4) {
    float a[4][8], b[4][8];
#pragma unroll
    for (int u = 0; u < 4; ++u) {
      *(float4*)(&a[u][0]) = *(const float4*)(&QsT[kk + u][ty8]);
      *(float4*)(&a[u][4]) = *(const float4*)(&QsT[kk + u][ty8 + 4]);
      *(float4*)(&b[u][0]) = *(const float4*)(&KsT[kk + u][tx8]);
      *(float4*)(&b[u][4]) = *(const float4*)(&KsT[kk + u][tx8 + 4]);
    }
    // Per-element k order: kk outer, u inner ascending -> frozen chain.
#pragma unroll
    for (int i = 0; i < 8; ++i)
#pragma unroll
      for (int u = 0; u < 4; ++u)
#pragma unroll
        for (int j = 0; j < 8; ++j)
          acc[i][j] += a[u][i] * b[u][j];
  }

#pragma unroll
  for (int i = 0; i < 8; ++i) {
    float* orow = scores + ((size_t)bh * kS + q0 + ty8 + i) * kS + k0 + tx8;
    float4 o0 = make_float4(acc[i][0] * 0.125f, acc[i][1] * 0.125f,
                            acc[i][2] * 0.125f, acc[i][3] * 0.125f);
    float4 o1 = make_float4(acc[i][4] * 0.125f, acc[i][5] * 0.125f,
                            acc[i][6] * 0.125f, acc[i][7] * 0.125f);
    *(float4*)(orow)     = o0;
    *(float4*)(orow + 4) = o1;
  }
}

// ---------------------------------------------------------------------------
// Kernel 2 (unchanged from round 5): one 256-thread block per query row.
// Selection semantics identical to the round-4 pass:
//   t32 = 32nd-largest fp32 VALUE (duplicates counted), keep = score >= t32.
// ---------------------------------------------------------------------------
__global__ __launch_bounds__(256) void topk_softmax(const float* __restrict__ v,
                                                    float* __restrict__ ctx,
                                                    float* __restrict__ attn,
                                                    float* __restrict__ mask) {
  const int row  = blockIdx.x;     // bh*2048 + qi
  const int bh   = row >> 11;
  const int tid  = threadIdx.x;
  const int lane = tid & 63;
  const int wid  = tid >> 6;

  __shared__ unsigned s_hist[kBins];       // 16 KB
  __shared__ float    s_cand[kMaxCand];    // 1 KB
  __shared__ int      s_kidx[kKeepCap];
  __shared__ float    s_kw[kKeepCap];
  __shared__ float    s_wmax[4], s_wsum[4];
  __shared__ unsigned s_T[4];
  __shared__ unsigned s_nc, s_nk;
  __shared__ int      s_bstar, s_gabove;
  __shared__ float    s_t32;

  // P0: load scores (registers) + zero hist.
  const float* srow = attn + (size_t)row * kS;   // scores from kernel 1
  float4 l0 = *(const float4*)(srow + tid * 4);
  float4 l1 = *(const float4*)(srow + 1024 + tid * 4);
  float locv[8] = {l0.x, l0.y, l0.z, l0.w, l1.x, l1.y, l1.z, l1.w};
  int   loce[8];
#pragma unroll
  for (int j = 0; j < 8; ++j)
    loce[j] = (j < 4) ? (tid * 4 + j) : (1024 + tid * 4 + (j - 4));
#pragma unroll
  for (int i = 0; i < 4; ++i)
    *(uint4*)(&s_hist[tid * 16 + i * 4]) = make_uint4(0u, 0u, 0u, 0u);
  if (tid == 0) { s_nc = 0u; s_nk = 0u; }
  __syncthreads();

  // P1: histogram + per-wave max.
  unsigned bins[8];
  float pmax = locv[0];
#pragma unroll
  for (int j = 0; j < 8; ++j) {
    bins[j] = sortable_bits(locv[j]) >> 20;
    atomicAdd(&s_hist[bins[j]], 1u);
    pmax = fmaxf(pmax, locv[j]);
  }
#pragma unroll
  for (int off = 32; off >= 1; off >>= 1)
    pmax = fmaxf(pmax, __shfl_xor(pmax, off));
  if (lane == 0) s_wmax[wid] = pmax;
  __syncthreads();

  // P2: chunk sums (16 bins/thread) + in-wave suffix scan via shfl.
  unsigned lsum = 0;
#pragma unroll
  for (int j = 0; j < 16; ++j) lsum += s_hist[tid * 16 + j];
  unsigned sfx = lsum;
#pragma unroll
  for (int off = 1; off < 64; off <<= 1) {
    unsigned z = __shfl_down(sfx, off);
    if (lane + off < 64) sfx += z;
  }
  if (lane == 0) s_T[wid] = sfx;   // this wave's 64-chunk total
  __syncthreads();

  // P3: global suffix, locate pivot bin bstar and g_above.
  unsigned hi = 0;
#pragma unroll
  for (int w = 0; w < 4; ++w)
    if (w > wid) hi += s_T[w];
  unsigned gsfx  = sfx + hi;        // inclusive suffix (chunks >= mine)
  unsigned above = gsfx - lsum;     // exclusive
  if (gsfx >= (unsigned)kTopK && above < (unsigned)kTopK) {
    unsigned run = above;
    for (int j = 15; j >= 0; --j) {
      unsigned h = s_hist[tid * 16 + j];
      if (run < (unsigned)kTopK && run + h >= (unsigned)kTopK) {
        s_bstar  = tid * 16 + j;
        s_gabove = (int)run;        // elements in bins strictly above pivot
      }
      run += h;
    }
  }
  __syncthreads();
  const int   bstar  = s_bstar;
  const int   gabove = s_gabove;
  const float mx = fmaxf(fmaxf(s_wmax[0], s_wmax[1]),
                         fmaxf(s_wmax[2], s_wmax[3]));

  // P4: collect pivot-bin values.
#pragma unroll
  for (int j = 0; j < 8; ++j) {
    if ((int)bins[j] == bstar) {
      unsigned pos = atomicAdd(&s_nc, 1u);
      if (pos < (unsigned)kMaxCand) s_cand[pos] = locv[j];
    }
  }
  __syncthreads();
  const int m2 = (int)min(s_nc, (unsigned)kMaxCand);

  // P5: t32 = value with gabove+g < 32 <= gabove+g+e (equal values all share
  // the pivot bin, so e counted here is complete).
  for (int c = tid; c < m2; c += 256) {
    float x = s_cand[c];
    int g = 0, e = 0;
    for (int j2 = 0; j2 < m2; ++j2) {
      float y = s_cand[j2];
      g += (y > x);
      e += (y == x);
    }
    int G = gabove + g;
    if (G < kTopK && G + e >= kTopK) s_t32 = x;
  }
  __syncthreads();
  const float t32 = s_t32;

  // P6: weights, partial Z, kept-list for ctx.
  float w8[8];
  float psum = 0.0f;
#pragma unroll
  for (int j = 0; j < 8; ++j) {
    bool keep = (locv[j] >= t32);
    float wv = keep ? __expf(locv[j] - mx) : 0.0f;
    w8[j] = wv;
    psum += wv;
    if (keep) {
      unsigned p = atomicAdd(&s_nk, 1u);
      if (p < (unsigned)kKeepCap) { s_kidx[p] = loce[j]; s_kw[p] = wv; }
    }
  }
#pragma unroll
  for (int off = 32; off >= 1; off >>= 1)
    psum += __shfl_xor(psum, off);
  if (lane == 0) s_wsum[wid] = psum;
  __syncthreads();

  const float Z = s_wsum[0] + s_wsum[1] + s_wsum[2] + s_wsum[3];
  const float invZ = 1.0f / Z;

  // P7: write attn + mask straight from registers (coalesced float4).
  float* arow = attn + (size_t)row * kS;
  float* mrow = mask + (size_t)row * kS;
  float4 a0 = make_float4(w8[0] * invZ, w8[1] * invZ, w8[2] * invZ, w8[3] * invZ);
  float4 a1 = make_float4(w8[4] * invZ, w8[5] * invZ, w8[6] * invZ, w8[7] * invZ);
  float4 m0 = make_float4(locv[0] >= t32 ? 0.f : 1.f, locv[1] >= t32 ? 0.f : 1.f,
                          locv[2] >= t32 ? 0.f : 1.f, locv[3] >= t32 ? 0.f : 1.f);
  float4 m1 = make_float4(locv[4] >= t32 ? 0.f : 1.f, locv[5] >= t32 ? 0.f : 1.f,
                          locv[6] >= t32 ? 0.f : 1.f, locv[7] >= t32 ? 0.f : 1.f);
  *(float4*)(arow + tid * 4)        = a0;
  *(float4*)(arow + 1024 + tid * 4) = a1;
  *(float4*)(mrow + tid * 4)        = m0;
  *(float4*)(mrow + 1024 + tid * 4) = m1;

  // P8: context via wave 0 (lane = d), coalesced v reads, ~32 kept rows.
  if (tid < kD) {
    const int nk = (int)min(s_nk, (unsigned)kKeepCap);
    float acc = 0.0f;
    for (int c = 0; c < nk; ++c)
      acc += s_kw[c] * v[((size_t)bh * kS + s_kidx[c]) * kD + tid];
    ctx[(size_t)row * kD + tid] = acc * invZ;
  }
}

extern "C" void kernel_launch(void* const* d_in, const int* in_sizes, int n_in,
                              void* d_out, int out_size, void* d_ws, size_t ws_size,
                              hipStream_t stream) {
  const float* q = (const float*)d_in[0];
  const float* k = (const float*)d_in[1];
  const float* v = (const float*)d_in[2];
  float* out  = (float*)d_out;
  float* ctx  = out;
  float* attn = out + kCtxElems;
  float* mask = attn + kAttnElems;

  dim3 g1(kS / 128, kS / 128, kBH);
  qk_scores<<<g1, 256, 0, stream>>>(q, k, attn);
  topk_softmax<<<dim3(kBH * kS), 256, 0, stream>>>(v, ctx, attn, mask);
}